// Round 6
// baseline (145.790 us; speedup 1.0000x reference)
//
#include <hip/hip_runtime.h>
#include <hip/hip_bf16.h>

// SAGEConv mean-aggr: out_i = mean_{j->i} x_j @ W_l^T + b_l + x_i @ W_r^T
//
// R1: global fp32 atomics write through L2 -> 300 MB, 481 us. Dead end.
// R2: 49x redundant dst-scan, latency-bound -> 365 us.
// R3: counting-sort by dst-bucket + LDS fp-atomic agg -> 200 us.
// R4: occupancy/MLP/unsafeAtomicAdd: agg unchanged -> fp32 LDS atomic = CAS loop.
// R5: fixed-point u64 LDS atomics (native ds_add_u64): agg 69.5 -> <47 us,
//     total 141.7. proj_scatter now leads (48 us): proj re-loads the same
//     10 KB of weights from global 20x per thread -> ~38 M VMEM instructions.
// R6: (a) weights staged in LDS, 4 nodes per 16-lane group -> VMEM/node 24->5;
//     (b) proj/scatter blocks interleaved (blockIdx%3) for true overlap;
//     (c) agg: 256 buckets of 391 nodes -> exactly 1 block/CU, MLP=4 batch.

#define N_NODES 100000
#define N_EDGES 1600000
#define D_IN 128
#define D_OUT 5

#define HL_STRIDE 8

#define B_NODES 391                    // nodes per bucket
#define N_BUCKETS 256                  // 256*391 = 100096 >= N_NODES
#define CAP 7168                       // mean 6250, sigma ~79 -> +11 sigma

#define SC_EPT 8                       // edges per scatter thread
#define SC_EPB (256 * SC_EPT)          // 2048 edges per scatter block
#define SC_GRID 782                    // ceil(1.6M / 2048)

#define PROJ_NPB 64                    // nodes per proj block (16 groups x 4)
#define PROJ_BLOCKS 1564               // covers 100096 nodes
#define FUSED_GRID 2346                // 1564 proj + 782 scatter, interleaved

// fixed-point params for integer LDS accumulation
#define FXS 262144.0f                  // 2^18 scale
#define FXB 16777216u                  // 2^24 bias per addend
#define FXBF 16777216.0f
#define INV_FXS (1.0f / 262144.0f)

typedef unsigned long long u64;
typedef unsigned int u32;

// ---------------------------------------------------------------------------
// Fused kernel A. blockIdx%3==2 -> counting-sort scatter (sblk = blockIdx/3);
// else projection (pblk = (blockIdx/3)*2 + blockIdx%3, 64 nodes per block).
// ---------------------------------------------------------------------------
__global__ __launch_bounds__(256) void proj_scatter_kernel(
    const float* __restrict__ x,
    const float* __restrict__ Wl,
    const float* __restrict__ Wr,
    float* __restrict__ hl,             // [N_NODES][8], first 5 valid
    float* __restrict__ hr,             // [N_NODES][8], first 5 valid
    const int* __restrict__ ei,         // [2][N_EDGES]: row0 src, row1 dst
    unsigned int* __restrict__ sorted,  // [N_BUCKETS][CAP]
    int* __restrict__ cursor)           // [N_BUCKETS], zero-initialized
{
    __shared__ __align__(16) float smem[1280];   // proj: W staging (5 KB)
    const int tid = threadIdx.x;
    const int role = blockIdx.x % 3;

    if (role != 2) {
        // ---------------- projection ----------------
        const int pblk = (blockIdx.x / 3) * 2 + role;

        // stage W: smem[o*128 + d], o 0..4 = Wl rows, o 5..9 = Wr rows
        for (int i = tid; i < 320; i += 256) {
            float4 v = (i < 160) ? ((const float4*)Wl)[i]
                                 : ((const float4*)Wr)[i - 160];
            ((float4*)smem)[i] = v;
        }
        __syncthreads();

        const int g = tid >> 4;          // group 0..15
        const int k = tid & 15;          // lane within group
        const float* wk = smem + k * 8;  // W[o] slice at wk + o*128
        const int node0 = pblk * PROJ_NPB + g * 4;

#pragma unroll
        for (int it = 0; it < 4; ++it) {
            const int node = node0 + it;
            if (node < N_NODES) {
                const float4* xr = (const float4*)(x + (size_t)node * D_IN + k * 8);
                float4 x0 = xr[0];
                float4 x1 = xr[1];

                float s[10];
#pragma unroll
                for (int o = 0; o < 10; ++o) {
                    const float4* w4 = (const float4*)(wk + o * 128);
                    float4 w0 = w4[0];
                    float4 w1 = w4[1];
                    s[o] = x0.x * w0.x + x0.y * w0.y + x0.z * w0.z + x0.w * w0.w
                         + x1.x * w1.x + x1.y * w1.y + x1.z * w1.z + x1.w * w1.w;
                }

#pragma unroll
                for (int o = 0; o < 10; ++o) {
                    s[o] += __shfl_xor(s[o], 8, 64);
                    s[o] += __shfl_xor(s[o], 4, 64);
                    s[o] += __shfl_xor(s[o], 2, 64);
                    s[o] += __shfl_xor(s[o], 1, 64);
                }

                if (k == 0) {
                    float* pl = hl + (size_t)node * HL_STRIDE;
                    *(float4*)pl = make_float4(s[0], s[1], s[2], s[3]);
                    pl[4] = s[4];
                    float* pr = hr + (size_t)node * HL_STRIDE;
                    *(float4*)pr = make_float4(s[5], s[6], s[7], s[8]);
                    pr[4] = s[9];
                }
            }
        }
    } else {
        // ---------------- counting-sort scatter ----------------
        int* hist    = (int*)smem;          // 256 ints
        int* basepos = hist + N_BUCKETS;    // 256 ints (2 KB total, fits)

        if (tid < N_BUCKETS) hist[tid] = 0;
        __syncthreads();

        const int blk = blockIdx.x / 3;
        const int e0  = blk * SC_EPB + tid * SC_EPT;

        int srcv[SC_EPT], dstv[SC_EPT], slot[SC_EPT];
        bool valid[SC_EPT];

        if (e0 + SC_EPT <= N_EDGES) {
            const int4* s4 = (const int4*)(ei + e0);
            const int4* d4 = (const int4*)(ei + N_EDGES + e0);
            int4 sa = s4[0], sb = s4[1], da = d4[0], db = d4[1];
            srcv[0]=sa.x; srcv[1]=sa.y; srcv[2]=sa.z; srcv[3]=sa.w;
            srcv[4]=sb.x; srcv[5]=sb.y; srcv[6]=sb.z; srcv[7]=sb.w;
            dstv[0]=da.x; dstv[1]=da.y; dstv[2]=da.z; dstv[3]=da.w;
            dstv[4]=db.x; dstv[5]=db.y; dstv[6]=db.z; dstv[7]=db.w;
#pragma unroll
            for (int q = 0; q < SC_EPT; ++q) valid[q] = true;
        } else {
#pragma unroll
            for (int q = 0; q < SC_EPT; ++q) {
                int e = e0 + q;
                valid[q] = (e < N_EDGES);
                srcv[q] = valid[q] ? ei[e] : 0;
                dstv[q] = valid[q] ? ei[N_EDGES + e] : 0;
            }
        }

#pragma unroll
        for (int q = 0; q < SC_EPT; ++q) {
            if (valid[q]) {
                unsigned b = (unsigned)dstv[q] / 391u;
                slot[q] = atomicAdd(&hist[b], 1);
            }
        }
        __syncthreads();

        if (tid < N_BUCKETS) {
            int c = hist[tid];
            if (c > 0) basepos[tid] = atomicAdd(&cursor[tid], c);
        }
        __syncthreads();

#pragma unroll
        for (int q = 0; q < SC_EPT; ++q) {
            if (valid[q]) {
                unsigned b = (unsigned)dstv[q] / 391u;
                unsigned r = (unsigned)dstv[q] - b * 391u;
                unsigned rec = (r << 17) | (unsigned)srcv[q];
                sorted[(size_t)b * CAP + basepos[b] + slot[q]] = rec;
            }
        }
    }
}

// ---------------------------------------------------------------------------
// Kernel B: per-bucket aggregation via native u64 LDS atomics, fixed-point
// biased fields (f*2^18 + 2^24 per addend; deg<=~100 keeps sums < 2^31).
// 256 blocks (1/CU) x 1024 threads. Gathers batched 4-wide before converts.
// ---------------------------------------------------------------------------
__global__ __launch_bounds__(1024) void agg_kernel(
    const unsigned int* __restrict__ sorted,
    const int* __restrict__ cursor,
    const float* __restrict__ hl,
    const float* __restrict__ hr,
    const float* __restrict__ bias,
    float* __restrict__ out)
{
    __shared__ u64 acc[B_NODES * 3];   // 9.4 KB

    const int b   = blockIdx.x;
    const int tid = threadIdx.x;

    for (int i = tid; i < B_NODES * 3; i += 1024) acc[i] = 0ull;
    __syncthreads();

    const int cnt = cursor[b];
    const unsigned int* sp = sorted + (size_t)b * CAP;
    const int nvec = cnt >> 2;

    for (int it = tid; it < nvec; it += 1024) {
        uint4 v = ((const uint4*)sp)[it];
        int s0 = (int)(v.x & 0x1FFFFu), r0 = (int)(v.x >> 17);
        int s1 = (int)(v.y & 0x1FFFFu), r1 = (int)(v.y >> 17);
        int s2 = (int)(v.z & 0x1FFFFu), r2 = (int)(v.z >> 17);
        int s3 = (int)(v.w & 0x1FFFFu), r3 = (int)(v.w >> 17);

        const float* p0 = hl + (size_t)s0 * HL_STRIDE;
        const float* p1 = hl + (size_t)s1 * HL_STRIDE;
        const float* p2 = hl + (size_t)s2 * HL_STRIDE;
        const float* p3 = hl + (size_t)s3 * HL_STRIDE;
        float4 h0 = *(const float4*)p0; float e0 = p0[4];
        float4 h1 = *(const float4*)p1; float e1 = p1[4];
        float4 h2 = *(const float4*)p2; float e2 = p2[4];
        float4 h3 = *(const float4*)p3; float e3 = p3[4];

#define EMIT(hh, ee, rr)                                                     \
        {                                                                    \
            u32 f0 = __float2uint_rn(fmaf((hh).x, FXS, FXBF));               \
            u32 f1 = __float2uint_rn(fmaf((hh).y, FXS, FXBF));               \
            u32 f2 = __float2uint_rn(fmaf((hh).z, FXS, FXBF));               \
            u32 f3 = __float2uint_rn(fmaf((hh).w, FXS, FXBF));               \
            u32 f4 = __float2uint_rn(fmaf((ee),   FXS, FXBF));               \
            u64* a = acc + (rr) * 3;                                         \
            atomicAdd(&a[0], ((u64)f1 << 32) | f0);                          \
            atomicAdd(&a[1], ((u64)f3 << 32) | f2);                          \
            atomicAdd(&a[2], ((u64)f4 << 32) | 1u);                          \
        }
        EMIT(h0, e0, r0) EMIT(h1, e1, r1) EMIT(h2, e2, r2) EMIT(h3, e3, r3)
    }
    for (int i = (nvec << 2) + tid; i < cnt; i += 1024) {
        unsigned int v = sp[i];
        int src = (int)(v & 0x1FFFFu);
        int r   = (int)(v >> 17);
        const float* p = hl + (size_t)src * HL_STRIDE;
        float4 h = *(const float4*)p;
        float  e = p[4];
        EMIT(h, e, r)
    }
#undef EMIT
    __syncthreads();

    const int nodebase = b * B_NODES;
    for (int n = tid; n < B_NODES; n += 1024) {
        int node = nodebase + n;
        if (node >= N_NODES) continue;
        u64 w0 = acc[n * 3 + 0];
        u64 w1 = acc[n * 3 + 1];
        u64 w2 = acc[n * 3 + 2];
        u32 deg = (u32)(w2 & 0xFFFFFFFFu);
        u32 db  = deg * FXB;            // wraparound-safe: true values fit i32
        int i0 = (int)((u32)(w0 & 0xFFFFFFFFu) - db);
        int i1 = (int)((u32)(w0 >> 32)         - db);
        int i2 = (int)((u32)(w1 & 0xFFFFFFFFu) - db);
        int i3 = (int)((u32)(w1 >> 32)         - db);
        int i4 = (int)((u32)(w2 >> 32)         - db);

        float rec = INV_FXS / fmaxf((float)deg, 1.0f);
        const float* h = hr + (size_t)node * HL_STRIDE;
        float* o = out + (size_t)node * 5;
        o[0] = (float)i0 * rec + bias[0] + h[0];
        o[1] = (float)i1 * rec + bias[1] + h[1];
        o[2] = (float)i2 * rec + bias[2] + h[2];
        o[3] = (float)i3 * rec + bias[3] + h[3];
        o[4] = (float)i4 * rec + bias[4] + h[4];
    }
}

extern "C" void kernel_launch(void* const* d_in, const int* in_sizes, int n_in,
                              void* d_out, int out_size, void* d_ws, size_t ws_size,
                              hipStream_t stream) {
    const float* x    = (const float*)d_in[0];
    const int*   ei   = (const int*)d_in[1];
    const float* Wl   = (const float*)d_in[2];
    const float* bl   = (const float*)d_in[3];
    const float* Wr   = (const float*)d_in[4];
    float*       out  = (float*)d_out;

    // workspace layout (16B-aligned): ~13.8 MB total
    float*        hl     = (float*)d_ws;                              // 800000 f
    float*        hr     = hl + (size_t)N_NODES * HL_STRIDE;          // 800000 f
    unsigned int* sorted = (unsigned int*)(hr + (size_t)N_NODES * HL_STRIDE); // 256*7168
    int*          cursor = (int*)(sorted + (size_t)N_BUCKETS * CAP);  // 256 i32

    hipMemsetAsync(cursor, 0, N_BUCKETS * sizeof(int), stream);

    proj_scatter_kernel<<<FUSED_GRID, 256, 0, stream>>>(
        x, Wl, Wr, hl, hr, ei, sorted, cursor);

    agg_kernel<<<N_BUCKETS, 1024, 0, stream>>>(sorted, cursor, hl, hr, bl, out);
}